// Round 6
// baseline (1915.629 us; speedup 1.0000x reference)
//
#include <hip/hip_runtime.h>

typedef unsigned short u16;
typedef unsigned long long u64;
typedef __attribute__((ext_vector_type(8))) short bf8;
typedef __attribute__((ext_vector_type(4))) float fx4;

#define N_ENT   100000
#define N_EDGE  500000
#define N_TEST  131072
#define EDIM    200
#define AE_LD   224     // all_ent leading dim (200 valid + 24 zero pad)
#define NB_SCAN 391     // ceil(100000/256)

// ---------- helpers ----------
__device__ __forceinline__ u16 f2bf(float f) {
  union { float f; unsigned u; } c; c.f = f;
  return (u16)((c.u + 0x7FFFu + ((c.u >> 16) & 1u)) >> 16);  // RNE
}
__device__ __forceinline__ float bf2f(u16 h) {
  union { unsigned u; float f; } c; c.u = ((unsigned)h) << 16;
  return c.f;
}
// async global->LDS, 16B per lane; LDS dest = wave-uniform base + lane*16
__device__ __forceinline__ void gload16(const u16* g, u16* l) {
  __builtin_amdgcn_global_load_lds(
      (const __attribute__((address_space(1))) void*)g,
      (__attribute__((address_space(3))) void*)l, 16, 0, 0);
}

// ---------- generic bf16 MFMA GEMM: out = act(A @ B^T + bias) ----------
// PROVEN STRUCTURE: 128x128 tile, 4 waves, single-buffered LDS, 2 barriers
// per K-step, ~3 blocks/CU (inter-block overlap hides the drain, m114).
// r5 lesson: at BK=32 this sits at the m97-structure ceiling (~323 TF @
// N=2048, matches guide m102). The barrier drain is paid once per K-step,
// so BKT=64 (template param) halves the drain count for K%64==0 GEMMs
// (phase-4) while keeping LDS at 32 KB (occupancy preserved; m132's BK=128
// regression was the 64 KB LDS cliff, avoided here).
// Staging swizzle (both-sides involution, m104/m136):
//   BKT=32: chunk=16rx4slots, src slot ^= (row>>1)&3, read slot = fq^((fr>>1)&3)
//   BKT=64: chunk=8rx8slots,  src slot ^= row&7,      read slot = (kk*4+fq)^(fr&7)
// both give ~2-way bank windows (free). r3-verified at BKT=32 (0.52M confl).
// idxMode: 0 none (clamp at mClamp), 2 rowIdx[2*gm], 3 rowIdx[2*gm+1],
//          4 dual-gather: cols <224 from rowIdx[2*gm], cols >=224 from rowIdx[2*gm+1]
// act: 0 none | 1 tanh | 3 dot-vs-qbuf -> dotOut (atta) | 4 lrelu,dot-auxF -> dotOut (logit)
//      5 store lrelu(acc + bias + dotOut[row]*auxF[col])
#define EPS 72   // epilogue LDS row stride (u16)

template<int TM, int WN, int BKT>
__global__ __launch_bounds__(64 * 2 * WN) void gemm_t(
    const u16* __restrict__ A, long lda,
    const u16* __restrict__ B, long ldb,
    u16* __restrict__ out, long ldOut,
    int K,
    const int* __restrict__ rowIdx, int idxMode, int mClamp,
    int mValid, int nValid, int nStore,
    const float* __restrict__ bias, int act, float slope,
    const u16* __restrict__ qbuf, const float* __restrict__ auxF,
    float* __restrict__ dotOut)
{
  constexpr int BM = TM * 32;        // 2 wave-rows x TM*16
  constexpr int BN = WN * 64;
  constexpr int WAVES = 2 * WN;
  constexpr int RPC = 512 / BKT;     // rows per staged chunk (64 lanes x 16B)
  constexpr int NCH = 32 / RPC;      // chunks per wave's 32-row slab
  constexpr int KPL = BKT / 32;      // 32-wide k-slices per LDS tile
  constexpr int STG = (BM + BN) * BKT;          // staging u16
  constexpr int EPT = WAVES * 32 * EPS;         // epilogue u16
  constexpr int SMEMU = (STG > EPT) ? STG : EPT;
  __shared__ __align__(16) u16 smem[SMEMU];
  u16* As = smem;                 // BM*BKT u16
  u16* Bs = smem + BM * BKT;      // BN*BKT u16
  const int tid  = threadIdx.x;
  const int wave = tid >> 6, lane = tid & 63;
  const int wr = (wave / WN) * (TM * 16), wc = (wave % WN) * 64;
  const int fr = lane & 15, fq = lane >> 4;
  const long bm = (long)blockIdx.x * BM, bn = (long)blockIdx.y * BN;

  // staging setup: wave stages rows [wave*32, +32) of A and B as NCH chunks.
  const int srow = wave * 32;
  const int lrow = lane / (BKT / 8);            // row within chunk
  int slot;
  if constexpr (BKT == 32) slot = (lane & 3) ^ ((lane >> 3) & 3);
  else                     slot = (lane & 7) ^ (lrow & 7);
  const int kc = slot * 8;                      // swizzled source u16 col
  long a0[NCH], a1[NCH], boff[NCH];
  #pragma unroll
  for (int h = 0; h < NCH; ++h) {
    long gmRow = bm + srow + h * RPC + lrow;
    long b0, b1;
    if (idxMode == 0) {
      long gm = (gmRow >= mClamp) ? (mClamp - 1) : gmRow;   // values unused (store-guarded)
      b0 = gm * lda; b1 = b0;
    } else if (idxMode == 2) {
      b0 = (long)rowIdx[2 * gmRow] * lda; b1 = b0;
    } else if (idxMode == 3) {
      b0 = (long)rowIdx[2 * gmRow + 1] * lda; b1 = b0;
    } else { // 4: dual
      b0 = (long)rowIdx[2 * gmRow] * lda;
      b1 = (long)rowIdx[2 * gmRow + 1] * lda - 224;
    }
    a0[h] = b0 + kc; a1[h] = b1 + kc;
    boff[h] = (bn + srow + h * RPC + lrow) * ldb + kc;
  }

  fx4 zero4 = {0.f, 0.f, 0.f, 0.f};
  fx4 acc[TM][4];
  #pragma unroll
  for (int i = 0; i < TM; ++i)
    #pragma unroll
    for (int j = 0; j < 4; ++j) acc[i][j] = zero4;

  for (int k0 = 0; k0 < K; k0 += BKT) {
    __syncthreads();                     // prev tile's ds_reads done
    const bool lo = (k0 + kc) < 224;     // per-lane; 16B slots never straddle 224
    #pragma unroll
    for (int h = 0; h < NCH; ++h) {
      const long ao = (idxMode == 4) ? (lo ? a0[h] : a1[h]) : a0[h];
      gload16(A + ao + k0, &As[(srow + h * RPC) * BKT]);
      gload16(B + boff[h] + k0, &Bs[(srow + h * RPC) * BKT]);
    }
    __syncthreads();                     // staging complete (vmcnt drained)
    #pragma unroll
    for (int kk = 0; kk < KPL; ++kk) {
      int rslot;
      if constexpr (BKT == 32) rslot = (fq ^ ((fr >> 1) & 3)) * 8;
      else                     rslot = ((kk * 4 + fq) ^ (fr & 7)) * 8;
      bf8 aF[TM], bF[4];
      #pragma unroll
      for (int mt = 0; mt < TM; ++mt)
        aF[mt] = *(const bf8*)&As[(wr + mt * 16 + fr) * BKT + rslot];
      #pragma unroll
      for (int nt = 0; nt < 4; ++nt)
        bF[nt] = *(const bf8*)&Bs[(wc + nt * 16 + fr) * BKT + rslot];
      #pragma unroll
      for (int mt = 0; mt < TM; ++mt)
        #pragma unroll
        for (int nt = 0; nt < 4; ++nt)
          acc[mt][nt] = __builtin_amdgcn_mfma_f32_16x16x32_bf16(aF[mt], bF[nt], acc[mt][nt], 0, 0, 0);
    }
  }

  // C/D layout: col=lane&15, row=(lane>>4)*4+reg  [m89-verified]
  if (act == 3 || act == 4) {
    #pragma unroll
    for (int mt = 0; mt < TM; ++mt) {
      #pragma unroll
      for (int r = 0; r < 4; ++r) {
        const long gm = bm + wr + mt * 16 + fq * 4 + r;
        float p = 0.f;
        #pragma unroll
        for (int nt = 0; nt < 4; ++nt) {
          const long gn = bn + wc + nt * 16 + fr;
          float v = acc[mt][nt][r] + bias[gn];
          if (act == 3) p += v * bf2f(qbuf[gm * 128 + gn]);
          else { v = (v >= 0.f) ? v : v * slope; p += v * auxF[gn]; }
        }
        p += __shfl_xor(p, 1, 64); p += __shfl_xor(p, 2, 64);
        p += __shfl_xor(p, 4, 64); p += __shfl_xor(p, 8, 64);
        if (fr == 0 && gm < mValid)
          atomicAdd(&dotOut[gm], (act == 3) ? p * 0.07071067811865475f : p);  // 1/sqrt(200)
      }
    }
    return;
  }

  // store epilogue: wave tile (TM*16 x 64) in 32-row passes through a private
  // 32xEPS LDS region (wave-local ordering only; no cross-wave sync needed).
  __syncthreads();                       // all ds_reads of As/Bs complete before reuse
  u16* ep = smem + wave * (32 * EPS);
  #pragma unroll
  for (int p = 0; p < TM / 2; ++p) {
    #pragma unroll
    for (int mt2 = 0; mt2 < 2; ++mt2) {
      const int mt = 2 * p + mt2;
      #pragma unroll
      for (int r = 0; r < 4; ++r) {
        const int lrl = mt2 * 16 + fq * 4 + r;       // row within the 32-row pass
        const long gm = bm + wr + mt * 16 + fq * 4 + r;
        const float attaV = (act == 5) ? dotOut[gm] : 0.f;
        #pragma unroll
        for (int nt = 0; nt < 4; ++nt) {
          const long gn = bn + wc + nt * 16 + fr;
          float v = 0.f;
          if (gn < nValid) {
            v = acc[mt][nt][r];
            if (bias) v += bias[gn];
            if (act == 1) v = tanhf(v);
            else if (act == 5) { v += attaV * auxF[gn]; v = (v >= 0.f) ? v : v * slope; }
          }
          ep[lrl * EPS + nt * 16 + fr] = f2bf(v);
        }
      }
    }
    // wave-local readback (compiler inserts lgkmcnt waits); 4 dwordx4 stores/lane
    #pragma unroll
    for (int it = 0; it < 4; ++it) {
      const int lr = it * 8 + (lane >> 3);
      const int lc = (lane & 7) * 8;
      const long gm = bm + wr + p * 32 + lr;
      const long gn = bn + wc + lc;
      if (gm < mValid && gn + 7 < nStore)
        *(bf8*)(out + gm * ldOut + gn) = *(const bf8*)&ep[lr * EPS + lc];
    }
  }
}

// ---------- per-chunk test-row materialization (kills 16x random re-gather) ----------
// te_cat[r][0..223]   = all_ent[toTest[2r]][0..223]
// te_cat[r][224..447] = all_ent[toTest[2r+1]][0..223]
__global__ void gather_te(const int* __restrict__ toTest, const u16* __restrict__ all_ent,
                          u16* __restrict__ te_cat, int CH) {
  const int r = blockIdx.x * 4 + (threadIdx.x >> 6);
  if (r >= CH) return;
  const int lane = threadIdx.x & 63;
  u16* dst = te_cat + (size_t)r * 448;
  if (lane < 28) {
    const int i0 = toTest[2 * r];
    *(bf8*)(dst + lane * 8) = *(const bf8*)(all_ent + (size_t)i0 * AE_LD + lane * 8);
  } else if (lane < 56) {
    const int i1 = toTest[2 * r + 1];
    *(bf8*)(dst + 224 + (lane - 28) * 8) =
        *(const bf8*)(all_ent + (size_t)i1 * AE_LD + (lane - 28) * 8);
  }
}

// ---------- sorted-CSR edge aggregation ----------
__global__ void hist_kernel(const int* __restrict__ ei, int* __restrict__ cnt) {
  int e = blockIdx.x * 256 + threadIdx.x;
  if (e < N_EDGE) atomicAdd(&cnt[ei[N_EDGE + e]], 1);
}
__global__ void scanA_kernel(const int* __restrict__ cnt, int* __restrict__ offs,
                             int* __restrict__ blockSums) {
  __shared__ int s[256];
  int gid = blockIdx.x * 256 + threadIdx.x;
  int v = (gid < N_ENT) ? cnt[gid] : 0;
  s[threadIdx.x] = v;
  __syncthreads();
  for (int off = 1; off < 256; off <<= 1) {
    int t = (threadIdx.x >= off) ? s[threadIdx.x - off] : 0;
    __syncthreads();
    s[threadIdx.x] += t;
    __syncthreads();
  }
  if (gid < N_ENT) offs[gid] = s[threadIdx.x] - v;
  if (threadIdx.x == 255) blockSums[blockIdx.x] = s[255];
}
__global__ void scanB_kernel(const int* __restrict__ blockSums, int* __restrict__ blockOffs) {
  __shared__ int s[512];
  int v = (threadIdx.x < NB_SCAN) ? blockSums[threadIdx.x] : 0;
  s[threadIdx.x] = v;
  __syncthreads();
  for (int off = 1; off < 512; off <<= 1) {
    int t = (threadIdx.x >= off) ? s[threadIdx.x - off] : 0;
    __syncthreads();
    s[threadIdx.x] += t;
    __syncthreads();
  }
  if (threadIdx.x < NB_SCAN) blockOffs[threadIdx.x] = s[threadIdx.x] - v;
}
__global__ void scanC_kernel(int* __restrict__ offs, const int* __restrict__ blockOffs) {
  int gid = blockIdx.x * 256 + threadIdx.x;
  if (gid < N_ENT) offs[gid] += blockOffs[blockIdx.x];
}
__global__ void place_kernel(const int* __restrict__ ei, const int* __restrict__ et,
                             const int* __restrict__ offs, int* __restrict__ cursor,
                             int* __restrict__ sortedSrc, int* __restrict__ sortedT) {
  int e = blockIdx.x * 256 + threadIdx.x;
  if (e >= N_EDGE) return;
  int dst = ei[N_EDGE + e];
  int pos = offs[dst] + atomicAdd(&cursor[dst], 1);
  sortedSrc[pos] = ei[e];
  sortedT[pos]   = et[e];
}
// wave-per-entity, float4: A1 row = [segsum(ent[src]-rel[t])*rsqrt(max(deg,1)) | ent_emb[r] | 0]
__global__ void agg_A1_kernel(const int* __restrict__ offs, const int* __restrict__ cnt,
                              const int* __restrict__ sortedSrc, const int* __restrict__ sortedT,
                              const float* __restrict__ ent_emb, const float* __restrict__ rel_emb,
                              u16* __restrict__ A1) {
  const int r = blockIdx.x * 4 + (threadIdx.x >> 6);
  if (r >= N_ENT) return;
  const int lane = threadIdx.x & 63;
  const int beg = offs[r], n = cnt[r];
  u16* row = A1 + (size_t)r * 416;
  if (lane < 50) {
    float4 a = {0.f, 0.f, 0.f, 0.f};
    for (int e = 0; e < n; ++e) {
      const int s = sortedSrc[beg + e], t = sortedT[beg + e];
      float4 x = ((const float4*)(ent_emb + (size_t)s * EDIM))[lane];
      float4 y = ((const float4*)(rel_emb + (size_t)t * EDIM))[lane];
      a.x += x.x - y.x; a.y += x.y - y.y; a.z += x.z - y.z; a.w += x.w - y.w;
    }
    const float nm = rsqrtf(fmaxf((float)n, 1.f));
    u64 p = (u64)f2bf(a.x * nm) | ((u64)f2bf(a.y * nm) << 16)
          | ((u64)f2bf(a.z * nm) << 32) | ((u64)f2bf(a.w * nm) << 48);
    *(u64*)(row + 4 * lane) = p;
    float4 e = ((const float4*)(ent_emb + (size_t)r * EDIM))[lane];
    u64 q = (u64)f2bf(e.x) | ((u64)f2bf(e.y) << 16)
          | ((u64)f2bf(e.z) << 32) | ((u64)f2bf(e.w) << 48);
    *(u64*)(row + 200 + 4 * lane) = q;
  }
  if (lane < 16) row[400 + lane] = 0;
}

// ---------- builders / precomputes ----------
__global__ void build_B1T(const float* __restrict__ W, const float* __restrict__ W_loop,
                          u16* __restrict__ B1T)
{
  int idx = blockIdx.x * 256 + threadIdx.x;
  if (idx >= 256 * 416) return;
  int n = idx / 416, k = idx % 416;
  float v = 0.f;
  if (n < 200) {
    if (k < 200) v = W[k * 200 + n];
    else if (k < 400) v = W_loop[(k - 200) * 200 + n];
  }
  B1T[idx] = f2bf(v);
}
__global__ void all_rel_kernel(const float* __restrict__ rel_emb, const float* __restrict__ W_rel,
                               float* __restrict__ all_rel)
{
  int r = blockIdx.x, c = threadIdx.x;
  if (c >= 200) return;
  const float* re = rel_emb + r * 200;
  float a = 0.f;
  for (int k = 0; k < 200; ++k) a += re[k] * W_rel[k * 200 + c];
  all_rel[r * 200 + c] = a;
}
// PQ[sel][m][n] = sum_r all_rel[r][sel*100+m] * w1[401+r][n]
__global__ void pq_kernel(const float* __restrict__ all_rel, const float* __restrict__ w1,
                          float* __restrict__ PQ) {
  int idx = blockIdx.x * 256 + threadIdx.x;
  if (idx >= 2 * 100 * 2048) return;
  int n = idx & 2047, m = (idx >> 11) % 100, sel = idx / 204800;
  float a = 0.f;
  for (int r = 0; r < 474; ++r)
    a += all_rel[r * 200 + sel * 100 + m] * w1[(size_t)(401 + r) * 2048 + n];
  PQ[idx] = a;
}
// P2[sel][k][n] = sum_m trans_w[k][m] * PQ[sel][m][n]
__global__ void p2_kernel(const float* __restrict__ trans_w, const float* __restrict__ PQ,
                          float* __restrict__ P2) {
  int idx = blockIdx.x * 256 + threadIdx.x;
  if (idx >= 2 * 200 * 2048) return;
  int n = idx & 2047, k = (idx >> 11) % 200, sel = idx / 409600;
  const float* pq = PQ + sel * 204800;
  float a = 0.f;
  for (int m = 0; m < 100; ++m) a += trans_w[k * 100 + m] * pq[m * 2048 + n];
  P2[idx] = a;
}
// W1eff [2048][448] B-layout: k<200: w1[k][n]+P2h ; 224<=k<424: w1[200+kk][n]-P2t ; else 0
__global__ void w1eff_kernel(const float* __restrict__ w1, const float* __restrict__ P2,
                             u16* __restrict__ W1eff) {
  int idx = blockIdx.x * 256 + threadIdx.x;
  if (idx >= 2048 * 448) return;
  int n = idx / 448, k = idx % 448;
  float v = 0.f;
  if (k < 200) v = w1[(size_t)k * 2048 + n] + P2[(size_t)k * 2048 + n];
  else if (k >= 224 && k < 424) {
    int kk = k - 224;
    v = w1[(size_t)(200 + kk) * 2048 + n] - P2[409600 + (size_t)kk * 2048 + n];
  }
  W1eff[idx] = f2bf(v);
}
__global__ void b1eff_kernel(const float* __restrict__ b1, const float* __restrict__ trans_b,
                             const float* __restrict__ PQ, float* __restrict__ b1eff) {
  int n = blockIdx.x * 256 + threadIdx.x;
  if (n >= 2048) return;
  float a = b1[n];
  for (int m = 0; m < 100; ++m)
    a += trans_b[m] * (PQ[m * 2048 + n] - PQ[204800 + m * 2048 + n]);
  b1eff[n] = a;
}
// qw2T/kw2T [128][224] B-layout: row j, col k<200: sum_m trans_w[k][m]*{q,k}_w[m][j]
__global__ void qkw2_kernel(const float* __restrict__ trans_w, const float* __restrict__ q_w,
                            const float* __restrict__ k_w, u16* __restrict__ qw2T,
                            u16* __restrict__ kw2T) {
  int idx = blockIdx.x * 256 + threadIdx.x;
  if (idx >= 128 * 224) return;
  int j = idx / 224, k = idx % 224;
  float a = 0.f, b = 0.f;
  if (k < 200)
    for (int m = 0; m < 100; ++m) {
      float t = trans_w[k * 100 + m];
      a += t * q_w[m * 128 + j];
      b += t * k_w[m * 128 + j];
    }
  qw2T[idx] = f2bf(a);
  kw2T[idx] = f2bf(b);
}
__global__ void qkb2_kernel(const float* __restrict__ q_b, const float* __restrict__ k_b,
                            const float* __restrict__ trans_b, const float* __restrict__ q_w,
                            const float* __restrict__ k_w, float* __restrict__ qb2,
                            float* __restrict__ kb2) {
  int j = threadIdx.x;
  if (j >= 128) return;
  float a = q_b[j], b = k_b[j];
  for (int m = 0; m < 100; ++m) {
    a += trans_b[m] * q_w[m * 128 + j];
    b += trans_b[m] * k_w[m * 128 + j];
  }
  qb2[j] = a; kb2[j] = b;
}
__global__ void build_w2T(const float* __restrict__ w2, u16* __restrict__ w2T)
{
  long idx = (long)blockIdx.x * 256 + threadIdx.x;
  if (idx >= (long)512 * 2048) return;
  int n = (int)(idx / 2048), k = (int)(idx % 2048);
  w2T[idx] = f2bf(w2[(size_t)k * 512 + n]);
}
__global__ void sigmoid_kernel(const float* __restrict__ logit, const float* __restrict__ b3,
                               float* __restrict__ out) {
  int i = blockIdx.x * 256 + threadIdx.x;
  if (i >= N_TEST) return;
  out[i] = 1.f / (1.f + __expf(-(logit[i] + b3[0])));
}

// ---------- host ----------
extern "C" void kernel_launch(void* const* d_in, const int* in_sizes, int n_in,
                              void* d_out, int out_size, void* d_ws, size_t ws_size,
                              hipStream_t stream)
{
  (void)in_sizes; (void)n_in; (void)out_size;
  const int*   edge_index = (const int*)d_in[0];
  const int*   edge_type  = (const int*)d_in[1];
  const int*   toTest     = (const int*)d_in[2];
  const float* ent_emb    = (const float*)d_in[3];
  const float* rel_emb    = (const float*)d_in[4];
  const float* W          = (const float*)d_in[5];
  const float* W_loop     = (const float*)d_in[6];
  const float* W_rel      = (const float*)d_in[7];
  const float* trans_w    = (const float*)d_in[8];
  const float* trans_b    = (const float*)d_in[9];
  const float* q_w        = (const float*)d_in[10];
  const float* q_b        = (const float*)d_in[11];
  const float* k_w        = (const float*)d_in[12];
  const float* k_b        = (const float*)d_in[13];
  const float* w1         = (const float*)d_in[14];
  const float* b1         = (const float*)d_in[15];
  const float* w2         = (const float*)d_in[16];
  const float* b2         = (const float*)d_in[17];
  const float* w3         = (const float*)d_in[18];
  const float* b3         = (const float*)d_in[19];
  float* out = (float*)d_out;

  // ---- workspace layout (lifetime overlays) ----
  unsigned char* ws = (unsigned char*)d_ws;
  float* atta    = (float*)(ws + 0);            //   524,288
  float* logit   = (float*)(ws + 524288);       //   524,288
  float* allrel  = (float*)(ws + 1048576);      //   379,392 (474*200*4 pad)
  u16*   B1T     = (u16*)  (ws + 1427968);      //   212,992
  u16*   W1eff   = (u16*)  (ws + 1640960);      // 1,835,008 (2048*448*2)
  u16*   qw2T    = (u16*)  (ws + 3475968);      //    57,344
  u16*   kw2T    = (u16*)  (ws + 3533312);      //    57,344
  float* b1eff   = (float*)(ws + 3590656);      //     8,192
  float* qb2     = (float*)(ws + 3598848);      //     1,024 (pad)
  float* kb2     = (float*)(ws + 3599872);      //     1,024 (pad)
  u16*   w2T     = (u16*)  (ws + 3600896);      // 2,097,152
  const size_t X_base = 5698048;
  u16*   all_ent = (u16*)  (ws + X_base);                  // 44,800,000
  u16*   Qbuf    = (u16*)  (ws + X_base + 44800000);       // 33,554,432
  const size_t Y_base = 84052480;
  u16*   A1      = (u16*)  (ws + Y_base);       // 83,200,000 (dead after all_ent GEMM;
                                                //  reused per-chunk as te_cat[CH][448])
  const size_t Z_base = 167252480;

  // Z scratch (dead after precomputes, before h1 is written)
  int*   cnt       = (int*)  (ws + Z_base);
  int*   offs      = (int*)  (ws + Z_base + 400000);
  int*   cursor    = (int*)  (ws + Z_base + 800000);
  int*   blockSums = (int*)  (ws + Z_base + 1200000);
  int*   blockOffs = (int*)  (ws + Z_base + 1202048);
  int*   sortedSrc = (int*)  (ws + Z_base + 1204096);
  int*   sortedT   = (int*)  (ws + Z_base + 3204096);
  float* PQ        = (float*)(ws + Z_base + 5204096);   // 1,638,400
  float* P2        = (float*)(ws + Z_base + 6842496);   // 3,276,800 -> ends Z+10,119,296

  int CH;
  if      (Z_base + (size_t)65536  * 4096 <= ws_size) CH = 65536;
  else if (Z_base + (size_t)32768  * 4096 <= ws_size) CH = 32768;
  else if (Z_base + (size_t)16384  * 4096 <= ws_size) CH = 16384;
  else if (Z_base + (size_t)8192   * 4096 <= ws_size) CH = 8192;
  else return;
  // CH capped at 65536 so te_cat (CH*896 B) fits A1's 83.2 MB region.
  u16* h1     = (u16*)(ws + Z_base);             // CH*2048*2 (overlays dead scratch)
  u16* te_cat = A1;                              // CH*448 u16 (overlays dead A1)
  const int NC = N_TEST / CH;

  hipMemsetAsync(cnt, 0, 400000, stream);
  hipMemsetAsync(cursor, 0, 400000, stream);
  hipMemsetAsync(atta, 0, 524288, stream);
  hipMemsetAsync(logit, 0, 524288, stream);

  // phase 1: CSR aggregation -> A1
  hist_kernel<<<(N_EDGE + 255) / 256, 256, 0, stream>>>(edge_index, cnt);
  scanA_kernel<<<NB_SCAN, 256, 0, stream>>>(cnt, offs, blockSums);
  scanB_kernel<<<1, 512, 0, stream>>>(blockSums, blockOffs);
  scanC_kernel<<<NB_SCAN, 256, 0, stream>>>(offs, blockOffs);
  place_kernel<<<(N_EDGE + 255) / 256, 256, 0, stream>>>(edge_index, edge_type, offs, cursor,
                                                         sortedSrc, sortedT);
  agg_A1_kernel<<<(N_ENT + 3) / 4, 256, 0, stream>>>(offs, cnt, sortedSrc, sortedT,
                                                     ent_emb, rel_emb, A1);
  build_B1T<<<(256 * 416) / 256, 256, 0, stream>>>(W, W_loop, B1T);

  // all_ent = tanh([agg*norm | ent] @ [W ; W_loop]) -> bf16 [100000][224]
  gemm_t<4, 2, 32><<<dim3(782, 2), 256, 0, stream>>>(A1, 416, B1T, 416, all_ent, AE_LD,
      416, nullptr, 0, N_ENT, N_ENT, 200, AE_LD, nullptr, 1, 0.f, nullptr, nullptr, nullptr);

  // phase 2: folded-weight precomputes (f32; PQ/P2 die here)
  all_rel_kernel<<<474, 256, 0, stream>>>(rel_emb, W_rel, allrel);
  pq_kernel<<<(2 * 100 * 2048) / 256, 256, 0, stream>>>(allrel, w1, PQ);
  p2_kernel<<<(2 * 200 * 2048) / 256, 256, 0, stream>>>(trans_w, PQ, P2);
  w1eff_kernel<<<(2048 * 448) / 256, 256, 0, stream>>>(w1, P2, W1eff);
  b1eff_kernel<<<8, 256, 0, stream>>>(b1, trans_b, PQ, b1eff);
  qkw2_kernel<<<(128 * 224) / 256, 256, 0, stream>>>(trans_w, q_w, k_w, qw2T, kw2T);
  qkb2_kernel<<<1, 128, 0, stream>>>(q_b, k_b, trans_b, q_w, k_w, qb2, kb2);
  build_w2T<<<(512 * 2048) / 256, 256, 0, stream>>>(w2, w2T);

  // phase 3: atta = ((te0@qw2+qb2) . (te1@kw2+kb2)) / sqrt(200)  (gathered from all_ent)
  // N=128 -> single N-block (gather happens once; no re-fetch) -> keep in-GEMM gather.
  gemm_t<4, 2, 32><<<dim3(1024, 1), 256, 0, stream>>>(all_ent, AE_LD, qw2T, AE_LD, Qbuf, 128,
      AE_LD, toTest, 2, 0, N_TEST, 128, 128, qb2, 0, 0.f, nullptr, nullptr, nullptr);
  gemm_t<4, 2, 32><<<dim3(1024, 1), 256, 0, stream>>>(all_ent, AE_LD, kw2T, AE_LD, nullptr, 0,
      AE_LD, toTest, 3, 0, N_TEST, 128, 128, kb2, 3, 0.f, Qbuf, nullptr, atta);

  // phase 4: per-chunk  materialize te_cat = [te0-emb | te1-emb]  (random gather 1x),
  //          h1 = lrelu(te_cat @ W1eff + atta*w1[400,:] + b1eff)   (BKT=64: 7 K-steps),
  //          logit += rowdot(lrelu(h1 @ w2T + b2), w3)             (BKT=64: 32 K-steps)
  for (int c = 0; c < NC; ++c) {
    gather_te<<<CH / 4, 256, 0, stream>>>(toTest + (size_t)c * CH * 2, all_ent, te_cat, CH);
    gemm_t<4, 2, 64><<<dim3(CH / 128, 16), 256, 0, stream>>>(te_cat, 448, W1eff, 448, h1, 2048,
        448, nullptr, 0, CH, CH, 2048, 2048, b1eff, 5, 0.0001f,
        nullptr, w1 + (size_t)400 * 2048, atta + (size_t)c * CH);
    gemm_t<4, 2, 64><<<dim3(CH / 128, 4), 256, 0, stream>>>(h1, 2048, w2T, 2048, nullptr, 0,
        2048, nullptr, 0, CH, CH, 512, 512, b2, 4, 0.001f,
        nullptr, w3, logit + (size_t)c * CH);
  }
  sigmoid_kernel<<<N_TEST / 256, 256, 0, stream>>>(logit, b3, out);
}

// Round 7
// 1787.907 us; speedup vs baseline: 1.0714x; 1.0714x over previous
//
#include <hip/hip_runtime.h>

typedef unsigned short u16;
typedef unsigned long long u64;
typedef __attribute__((ext_vector_type(8))) short bf8;
typedef __attribute__((ext_vector_type(4))) float fx4;

#define N_ENT   100000
#define N_EDGE  500000
#define N_TEST  131072
#define EDIM    200
#define AE_LD   224     // all_ent leading dim (200 valid + 24 zero pad)
#define NB_SCAN 391     // ceil(100000/256)

// ---------- helpers ----------
__device__ __forceinline__ u16 f2bf(float f) {
  union { float f; unsigned u; } c; c.f = f;
  return (u16)((c.u + 0x7FFFu + ((c.u >> 16) & 1u)) >> 16);  // RNE
}
__device__ __forceinline__ float bf2f(u16 h) {
  union { unsigned u; float f; } c; c.u = ((unsigned)h) << 16;
  return c.f;
}
// async global->LDS, 16B per lane; LDS dest = wave-uniform base + lane*16
__device__ __forceinline__ void gload16(const u16* g, u16* l) {
  __builtin_amdgcn_global_load_lds(
      (const __attribute__((address_space(1))) void*)g,
      (__attribute__((address_space(3))) void*)l, 16, 0, 0);
}

// ---------- generic bf16 MFMA GEMM: out = act(A @ B^T + bias) ----------
// PROVEN ENGINE (r5: 186us GEMM1): 128x128 tile, 4 waves, BK=32, single-
// buffered LDS, 2 barriers/K-step, ~2.5 blocks/CU (overlap hides drain, m114).
// r3/r4/r6 lessons: 256^2 tile, HIP dbuf, BKT=64 ALL regress (occupancy or
// alias-drain); do not reduce blocks/CU in this structure.
// NEW (this round) T1 XCD swizzle [m204 bijective + N-fastest decode]:
// 1-D grid; orig%8 = XCD (HW round-robin); each XCD gets a contiguous wgid
// chunk; wgid decodes n-fastest -> all N-blocks of an M-panel run on ONE
// XCD -> B-matrix + gathered A-rows become L2-resident (4MB/XCD), cutting
// the staging-drain latency (~600cy L3 -> ~200cy L2) that dominates K-steps.
// Staging swizzle (r3-verified, conflicts 7.86M->0.52M): source-side 16B-slot
// ^= (row>>1)&3 with linear LDS dest (m104); read slot = fq^((fr>>1)&3).
// idxMode: 0 none (clamp at mClamp), 2 rowIdx[2*gm], 3 rowIdx[2*gm+1],
//          4 dual-gather: cols <224 from rowIdx[2*gm], cols >=224 from rowIdx[2*gm+1]
// act: 0 none | 1 tanh | 3 dot-vs-qbuf -> dotOut (atta) | 4 lrelu,dot-auxF -> dotOut (logit)
//      5 store lrelu(acc + bias + dotOut[row]*auxF[col])
#define BK 32
#define EPS 72   // epilogue LDS row stride (u16)

template<int TM, int WN>
__global__ __launch_bounds__(64 * 2 * WN) void gemm_t(
    const u16* __restrict__ A, long lda,
    const u16* __restrict__ B, long ldb,
    u16* __restrict__ out, long ldOut,
    int K, int NBN,
    const int* __restrict__ rowIdx, int idxMode, int mClamp,
    int mValid, int nValid, int nStore,
    const float* __restrict__ bias, int act, float slope,
    const u16* __restrict__ qbuf, const float* __restrict__ auxF,
    float* __restrict__ dotOut)
{
  constexpr int BM = TM * 32;        // 2 wave-rows x TM*16
  constexpr int BN = WN * 64;
  constexpr int WAVES = 2 * WN;
  // smem: staging As+Bs ((BM+BN)*BK u16) carved from the epilogue buffer
  // (WAVES*32*EPS u16 >= (BM+BN)*BK for the <4,2> instantiation)
  __shared__ __align__(16) u16 smem[WAVES * 32 * EPS];
  u16* As = smem;                // BM*BK u16
  u16* Bs = smem + BM * BK;      // BN*BK u16
  const int tid  = threadIdx.x;
  const int wave = tid >> 6, lane = tid & 63;
  const int wr = (wave / WN) * (TM * 16), wc = (wave % WN) * 64;
  const int fr = lane & 15, fq = lane >> 4;

  // T1: bijective XCD-chunked swizzle (m204) + n-fastest decode.
  // orig%8 tracks the HW XCD round-robin; each XCD gets a contiguous wgid
  // chunk; consecutive wgid within a chunk sweep N for a fixed M-panel.
  const int nwg = gridDim.x;
  const int orig = blockIdx.x;
  const int q = nwg >> 3, rr = nwg & 7;
  const int xcd = orig & 7, j = orig >> 3;
  const int wgid = (xcd < rr ? xcd * (q + 1) : rr * (q + 1) + (xcd - rr) * q) + j;
  const long bm = (long)(wgid / NBN) * BM;
  const long bn = (long)(wgid % NBN) * BN;

  // staging: wave stages rows [wave*32, +32) of A and B as 2 chunks of 16 rows;
  // chunk = 64 lanes x 16B; lane i -> row +i/4, swizzled 16B-slot (i&3)^((i>>3)&3).
  const int srow = wave * 32;
  const int kc = (((lane & 3) ^ ((lane >> 3) & 3)) * 8);   // swizzled source u16 col
  long a0[2], a1[2], boff[2];
  #pragma unroll
  for (int h = 0; h < 2; ++h) {
    long gmRow = bm + srow + h * 16 + (lane >> 2);
    long b0, b1;
    if (idxMode == 0) {
      long gm = (gmRow >= mClamp) ? (mClamp - 1) : gmRow;   // values unused (store-guarded)
      b0 = gm * lda; b1 = b0;
    } else if (idxMode == 2) {
      b0 = (long)rowIdx[2 * gmRow] * lda; b1 = b0;
    } else if (idxMode == 3) {
      b0 = (long)rowIdx[2 * gmRow + 1] * lda; b1 = b0;
    } else { // 4: dual
      b0 = (long)rowIdx[2 * gmRow] * lda;
      b1 = (long)rowIdx[2 * gmRow + 1] * lda - 224;
    }
    a0[h] = b0 + kc; a1[h] = b1 + kc;
    boff[h] = (bn + srow + h * 16 + (lane >> 2)) * ldb + kc;
  }

  fx4 zero4 = {0.f, 0.f, 0.f, 0.f};
  fx4 acc[TM][4];
  #pragma unroll
  for (int i = 0; i < TM; ++i)
    #pragma unroll
    for (int j2 = 0; j2 < 4; ++j2) acc[i][j2] = zero4;

  for (int k0 = 0; k0 < K; k0 += BK) {
    __syncthreads();                     // prev tile's ds_reads done
    const bool lo = (k0 + kc) < 224;     // chunk never straddles 224 (224 % 32 == 0)
    #pragma unroll
    for (int h = 0; h < 2; ++h) {
      const long ao = (idxMode == 4) ? (lo ? a0[h] : a1[h]) : a0[h];
      gload16(A + ao + k0, &As[(srow + h * 16) * BK]);
      gload16(B + boff[h] + k0, &Bs[(srow + h * 16) * BK]);
    }
    __syncthreads();                     // staging complete (vmcnt drained)
    bf8 aF[TM], bF[4];
    const int rslot = (fq ^ ((fr >> 1) & 3)) * 8;   // read-side involution
    #pragma unroll
    for (int mt = 0; mt < TM; ++mt)
      aF[mt] = *(const bf8*)&As[(wr + mt * 16 + fr) * BK + rslot];
    #pragma unroll
    for (int nt = 0; nt < 4; ++nt)
      bF[nt] = *(const bf8*)&Bs[(wc + nt * 16 + fr) * BK + rslot];
    #pragma unroll
    for (int mt = 0; mt < TM; ++mt)
      #pragma unroll
      for (int nt = 0; nt < 4; ++nt)
        acc[mt][nt] = __builtin_amdgcn_mfma_f32_16x16x32_bf16(aF[mt], bF[nt], acc[mt][nt], 0, 0, 0);
  }

  // C/D layout: col=lane&15, row=(lane>>4)*4+reg  [m89-verified]
  if (act == 3 || act == 4) {
    #pragma unroll
    for (int mt = 0; mt < TM; ++mt) {
      #pragma unroll
      for (int r = 0; r < 4; ++r) {
        const long gm = bm + wr + mt * 16 + fq * 4 + r;
        float p = 0.f;
        #pragma unroll
        for (int nt = 0; nt < 4; ++nt) {
          const long gn = bn + wc + nt * 16 + fr;
          float v = acc[mt][nt][r] + bias[gn];
          if (act == 3) p += v * bf2f(qbuf[gm * 128 + gn]);
          else { v = (v >= 0.f) ? v : v * slope; p += v * auxF[gn]; }
        }
        p += __shfl_xor(p, 1, 64); p += __shfl_xor(p, 2, 64);
        p += __shfl_xor(p, 4, 64); p += __shfl_xor(p, 8, 64);
        if (fr == 0 && gm < mValid)
          atomicAdd(&dotOut[gm], (act == 3) ? p * 0.07071067811865475f : p);  // 1/sqrt(200)
      }
    }
    return;
  }

  // store epilogue: wave tile (TM*16 x 64) in 32-row passes through a private
  // 32xEPS LDS region (wave-local ordering only; no cross-wave sync needed).
  __syncthreads();                       // all ds_reads of As/Bs complete before reuse
  u16* ep = smem + wave * (32 * EPS);
  #pragma unroll
  for (int p = 0; p < TM / 2; ++p) {
    #pragma unroll
    for (int mt2 = 0; mt2 < 2; ++mt2) {
      const int mt = 2 * p + mt2;
      #pragma unroll
      for (int r = 0; r < 4; ++r) {
        const int lrl = mt2 * 16 + fq * 4 + r;       // row within the 32-row pass
        const long gm = bm + wr + mt * 16 + fq * 4 + r;
        const float attaV = (act == 5) ? dotOut[gm] : 0.f;
        #pragma unroll
        for (int nt = 0; nt < 4; ++nt) {
          const long gn = bn + wc + nt * 16 + fr;
          float v = 0.f;
          if (gn < nValid) {
            v = acc[mt][nt][r];
            if (bias) v += bias[gn];
            if (act == 1) v = tanhf(v);
            else if (act == 5) { v += attaV * auxF[gn]; v = (v >= 0.f) ? v : v * slope; }
          }
          ep[lrl * EPS + nt * 16 + fr] = f2bf(v);
        }
      }
    }
    // wave-local readback (compiler inserts lgkmcnt waits); 4 dwordx4 stores/lane
    #pragma unroll
    for (int it = 0; it < 4; ++it) {
      const int lr = it * 8 + (lane >> 3);
      const int lc = (lane & 7) * 8;
      const long gm = bm + wr + p * 32 + lr;
      const long gn = bn + wc + lc;
      if (gm < mValid && gn + 7 < nStore)
        *(bf8*)(out + gm * ldOut + gn) = *(const bf8*)&ep[lr * EPS + lc];
    }
  }
}

// ---------- sorted-CSR edge aggregation ----------
__global__ void hist_kernel(const int* __restrict__ ei, int* __restrict__ cnt) {
  int e = blockIdx.x * 256 + threadIdx.x;
  if (e < N_EDGE) atomicAdd(&cnt[ei[N_EDGE + e]], 1);
}
__global__ void scanA_kernel(const int* __restrict__ cnt, int* __restrict__ offs,
                             int* __restrict__ blockSums) {
  __shared__ int s[256];
  int gid = blockIdx.x * 256 + threadIdx.x;
  int v = (gid < N_ENT) ? cnt[gid] : 0;
  s[threadIdx.x] = v;
  __syncthreads();
  for (int off = 1; off < 256; off <<= 1) {
    int t = (threadIdx.x >= off) ? s[threadIdx.x - off] : 0;
    __syncthreads();
    s[threadIdx.x] += t;
    __syncthreads();
  }
  if (gid < N_ENT) offs[gid] = s[threadIdx.x] - v;
  if (threadIdx.x == 255) blockSums[blockIdx.x] = s[255];
}
__global__ void scanB_kernel(const int* __restrict__ blockSums, int* __restrict__ blockOffs) {
  __shared__ int s[512];
  int v = (threadIdx.x < NB_SCAN) ? blockSums[threadIdx.x] : 0;
  s[threadIdx.x] = v;
  __syncthreads();
  for (int off = 1; off < 512; off <<= 1) {
    int t = (threadIdx.x >= off) ? s[threadIdx.x - off] : 0;
    __syncthreads();
    s[threadIdx.x] += t;
    __syncthreads();
  }
  if (threadIdx.x < NB_SCAN) blockOffs[threadIdx.x] = s[threadIdx.x] - v;
}
__global__ void scanC_kernel(int* __restrict__ offs, const int* __restrict__ blockOffs) {
  int gid = blockIdx.x * 256 + threadIdx.x;
  if (gid < N_ENT) offs[gid] += blockOffs[blockIdx.x];
}
__global__ void place_kernel(const int* __restrict__ ei, const int* __restrict__ et,
                             const int* __restrict__ offs, int* __restrict__ cursor,
                             int* __restrict__ sortedSrc, int* __restrict__ sortedT) {
  int e = blockIdx.x * 256 + threadIdx.x;
  if (e >= N_EDGE) return;
  int dst = ei[N_EDGE + e];
  int pos = offs[dst] + atomicAdd(&cursor[dst], 1);
  sortedSrc[pos] = ei[e];
  sortedT[pos]   = et[e];
}
// wave-per-entity, float4: A1 row = [segsum(ent[src]-rel[t])*rsqrt(max(deg,1)) | ent_emb[r] | 0]
__global__ void agg_A1_kernel(const int* __restrict__ offs, const int* __restrict__ cnt,
                              const int* __restrict__ sortedSrc, const int* __restrict__ sortedT,
                              const float* __restrict__ ent_emb, const float* __restrict__ rel_emb,
                              u16* __restrict__ A1) {
  const int r = blockIdx.x * 4 + (threadIdx.x >> 6);
  if (r >= N_ENT) return;
  const int lane = threadIdx.x & 63;
  const int beg = offs[r], n = cnt[r];
  u16* row = A1 + (size_t)r * 416;
  if (lane < 50) {
    float4 a = {0.f, 0.f, 0.f, 0.f};
    for (int e = 0; e < n; ++e) {
      const int s = sortedSrc[beg + e], t = sortedT[beg + e];
      float4 x = ((const float4*)(ent_emb + (size_t)s * EDIM))[lane];
      float4 y = ((const float4*)(rel_emb + (size_t)t * EDIM))[lane];
      a.x += x.x - y.x; a.y += x.y - y.y; a.z += x.z - y.z; a.w += x.w - y.w;
    }
    const float nm = rsqrtf(fmaxf((float)n, 1.f));
    u64 p = (u64)f2bf(a.x * nm) | ((u64)f2bf(a.y * nm) << 16)
          | ((u64)f2bf(a.z * nm) << 32) | ((u64)f2bf(a.w * nm) << 48);
    *(u64*)(row + 4 * lane) = p;
    float4 e = ((const float4*)(ent_emb + (size_t)r * EDIM))[lane];
    u64 q = (u64)f2bf(e.x) | ((u64)f2bf(e.y) << 16)
          | ((u64)f2bf(e.z) << 32) | ((u64)f2bf(e.w) << 48);
    *(u64*)(row + 200 + 4 * lane) = q;
  }
  if (lane < 16) row[400 + lane] = 0;
}

// ---------- builders / precomputes ----------
__global__ void build_B1T(const float* __restrict__ W, const float* __restrict__ W_loop,
                          u16* __restrict__ B1T)
{
  int idx = blockIdx.x * 256 + threadIdx.x;
  if (idx >= 256 * 416) return;
  int n = idx / 416, k = idx % 416;
  float v = 0.f;
  if (n < 200) {
    if (k < 200) v = W[k * 200 + n];
    else if (k < 400) v = W_loop[(k - 200) * 200 + n];
  }
  B1T[idx] = f2bf(v);
}
__global__ void all_rel_kernel(const float* __restrict__ rel_emb, const float* __restrict__ W_rel,
                               float* __restrict__ all_rel)
{
  int r = blockIdx.x, c = threadIdx.x;
  if (c >= 200) return;
  const float* re = rel_emb + r * 200;
  float a = 0.f;
  for (int k = 0; k < 200; ++k) a += re[k] * W_rel[k * 200 + c];
  all_rel[r * 200 + c] = a;
}
// PQ[sel][m][n] = sum_r all_rel[r][sel*100+m] * w1[401+r][n]
__global__ void pq_kernel(const float* __restrict__ all_rel, const float* __restrict__ w1,
                          float* __restrict__ PQ) {
  int idx = blockIdx.x * 256 + threadIdx.x;
  if (idx >= 2 * 100 * 2048) return;
  int n = idx & 2047, m = (idx >> 11) % 100, sel = idx / 204800;
  float a = 0.f;
  for (int r = 0; r < 474; ++r)
    a += all_rel[r * 200 + sel * 100 + m] * w1[(size_t)(401 + r) * 2048 + n];
  PQ[idx] = a;
}
// P2[sel][k][n] = sum_m trans_w[k][m] * PQ[sel][m][n]
__global__ void p2_kernel(const float* __restrict__ trans_w, const float* __restrict__ PQ,
                          float* __restrict__ P2) {
  int idx = blockIdx.x * 256 + threadIdx.x;
  if (idx >= 2 * 200 * 2048) return;
  int n = idx & 2047, k = (idx >> 11) % 200, sel = idx / 409600;
  const float* pq = PQ + sel * 204800;
  float a = 0.f;
  for (int m = 0; m < 100; ++m) a += trans_w[k * 100 + m] * pq[m * 2048 + n];
  P2[idx] = a;
}
// W1eff [2048][448] B-layout: k<200: w1[k][n]+P2h ; 224<=k<424: w1[200+kk][n]-P2t ; else 0
__global__ void w1eff_kernel(const float* __restrict__ w1, const float* __restrict__ P2,
                             u16* __restrict__ W1eff) {
  int idx = blockIdx.x * 256 + threadIdx.x;
  if (idx >= 2048 * 448) return;
  int n = idx / 448, k = idx % 448;
  float v = 0.f;
  if (k < 200) v = w1[(size_t)k * 2048 + n] + P2[(size_t)k * 2048 + n];
  else if (k >= 224 && k < 424) {
    int kk = k - 224;
    v = w1[(size_t)(200 + kk) * 2048 + n] - P2[409600 + (size_t)kk * 2048 + n];
  }
  W1eff[idx] = f2bf(v);
}
__global__ void b1eff_kernel(const float* __restrict__ b1, const float* __restrict__ trans_b,
                             const float* __restrict__ PQ, float* __restrict__ b1eff) {
  int n = blockIdx.x * 256 + threadIdx.x;
  if (n >= 2048) return;
  float a = b1[n];
  for (int m = 0; m < 100; ++m)
    a += trans_b[m] * (PQ[m * 2048 + n] - PQ[204800 + m * 2048 + n]);
  b1eff[n] = a;
}
// qw2T/kw2T [128][224] B-layout: row j, col k<200: sum_m trans_w[k][m]*{q,k}_w[m][j]
__global__ void qkw2_kernel(const float* __restrict__ trans_w, const float* __restrict__ q_w,
                            const float* __restrict__ k_w, u16* __restrict__ qw2T,
                            u16* __restrict__ kw2T) {
  int idx = blockIdx.x * 256 + threadIdx.x;
  if (idx >= 128 * 224) return;
  int j = idx / 224, k = idx % 224;
  float a = 0.f, b = 0.f;
  if (k < 200)
    for (int m = 0; m < 100; ++m) {
      float t = trans_w[k * 100 + m];
      a += t * q_w[m * 128 + j];
      b += t * k_w[m * 128 + j];
    }
  qw2T[idx] = f2bf(a);
  kw2T[idx] = f2bf(b);
}
__global__ void qkb2_kernel(const float* __restrict__ q_b, const float* __restrict__ k_b,
                            const float* __restrict__ trans_b, const float* __restrict__ q_w,
                            const float* __restrict__ k_w, float* __restrict__ qb2,
                            float* __restrict__ kb2) {
  int j = threadIdx.x;
  if (j >= 128) return;
  float a = q_b[j], b = k_b[j];
  for (int m = 0; m < 100; ++m) {
    a += trans_b[m] * q_w[m * 128 + j];
    b += trans_b[m] * k_w[m * 128 + j];
  }
  qb2[j] = a; kb2[j] = b;
}
__global__ void build_w2T(const float* __restrict__ w2, u16* __restrict__ w2T)
{
  long idx = (long)blockIdx.x * 256 + threadIdx.x;
  if (idx >= (long)512 * 2048) return;
  int n = (int)(idx / 2048), k = (int)(idx % 2048);
  w2T[idx] = f2bf(w2[(size_t)k * 512 + n]);
}
__global__ void sigmoid_kernel(const float* __restrict__ logit, const float* __restrict__ b3,
                               float* __restrict__ out) {
  int i = blockIdx.x * 256 + threadIdx.x;
  if (i >= N_TEST) return;
  out[i] = 1.f / (1.f + __expf(-(logit[i] + b3[0])));
}

// ---------- host ----------
extern "C" void kernel_launch(void* const* d_in, const int* in_sizes, int n_in,
                              void* d_out, int out_size, void* d_ws, size_t ws_size,
                              hipStream_t stream)
{
  (void)in_sizes; (void)n_in; (void)out_size;
  const int*   edge_index = (const int*)d_in[0];
  const int*   edge_type  = (const int*)d_in[1];
  const int*   toTest     = (const int*)d_in[2];
  const float* ent_emb    = (const float*)d_in[3];
  const float* rel_emb    = (const float*)d_in[4];
  const float* W          = (const float*)d_in[5];
  const float* W_loop     = (const float*)d_in[6];
  const float* W_rel      = (const float*)d_in[7];
  const float* trans_w    = (const float*)d_in[8];
  const float* trans_b    = (const float*)d_in[9];
  const float* q_w        = (const float*)d_in[10];
  const float* q_b        = (const float*)d_in[11];
  const float* k_w        = (const float*)d_in[12];
  const float* k_b        = (const float*)d_in[13];
  const float* w1         = (const float*)d_in[14];
  const float* b1         = (const float*)d_in[15];
  const float* w2         = (const float*)d_in[16];
  const float* b2         = (const float*)d_in[17];
  const float* w3         = (const float*)d_in[18];
  const float* b3         = (const float*)d_in[19];
  float* out = (float*)d_out;

  // ---- workspace layout (lifetime overlays) ----
  unsigned char* ws = (unsigned char*)d_ws;
  float* atta    = (float*)(ws + 0);            //   524,288
  float* logit   = (float*)(ws + 524288);       //   524,288
  float* allrel  = (float*)(ws + 1048576);      //   379,392 (474*200*4 pad)
  u16*   B1T     = (u16*)  (ws + 1427968);      //   212,992
  u16*   W1eff   = (u16*)  (ws + 1640960);      // 1,835,008 (2048*448*2)
  u16*   qw2T    = (u16*)  (ws + 3475968);      //    57,344
  u16*   kw2T    = (u16*)  (ws + 3533312);      //    57,344
  float* b1eff   = (float*)(ws + 3590656);      //     8,192
  float* qb2     = (float*)(ws + 3598848);      //     1,024 (pad)
  float* kb2     = (float*)(ws + 3599872);      //     1,024 (pad)
  u16*   w2T     = (u16*)  (ws + 3600896);      // 2,097,152
  const size_t X_base = 5698048;
  u16*   all_ent = (u16*)  (ws + X_base);                  // 44,800,000
  u16*   Qbuf    = (u16*)  (ws + X_base + 44800000);       // 33,554,432
  const size_t Y_base = 84052480;
  u16*   A1      = (u16*)  (ws + Y_base);       // 83,200,000 (dead after all_ent GEMM)
  const size_t Z_base = 167252480;

  // Z scratch (dead after precomputes, before h1 is written)
  int*   cnt       = (int*)  (ws + Z_base);
  int*   offs      = (int*)  (ws + Z_base + 400000);
  int*   cursor    = (int*)  (ws + Z_base + 800000);
  int*   blockSums = (int*)  (ws + Z_base + 1200000);
  int*   blockOffs = (int*)  (ws + Z_base + 1202048);
  int*   sortedSrc = (int*)  (ws + Z_base + 1204096);
  int*   sortedT   = (int*)  (ws + Z_base + 3204096);
  float* PQ        = (float*)(ws + Z_base + 5204096);   // 1,638,400
  float* P2        = (float*)(ws + Z_base + 6842496);   // 3,276,800 -> ends Z+10,119,296

  int CH;
  if      (Z_base + (size_t)131072 * 4096 <= ws_size) CH = 131072;
  else if (Z_base + (size_t)65536  * 4096 <= ws_size) CH = 65536;
  else if (Z_base + (size_t)32768  * 4096 <= ws_size) CH = 32768;
  else if (Z_base + (size_t)16384  * 4096 <= ws_size) CH = 16384;
  else if (Z_base + (size_t)8192   * 4096 <= ws_size) CH = 8192;
  else return;
  u16* h1 = (u16*)(ws + Z_base);                 // CH*2048*2 (overlays dead scratch)
  const int NC = N_TEST / CH;

  hipMemsetAsync(cnt, 0, 400000, stream);
  hipMemsetAsync(cursor, 0, 400000, stream);
  hipMemsetAsync(atta, 0, 524288, stream);
  hipMemsetAsync(logit, 0, 524288, stream);

  // phase 1: CSR aggregation -> A1
  hist_kernel<<<(N_EDGE + 255) / 256, 256, 0, stream>>>(edge_index, cnt);
  scanA_kernel<<<NB_SCAN, 256, 0, stream>>>(cnt, offs, blockSums);
  scanB_kernel<<<1, 512, 0, stream>>>(blockSums, blockOffs);
  scanC_kernel<<<NB_SCAN, 256, 0, stream>>>(offs, blockOffs);
  place_kernel<<<(N_EDGE + 255) / 256, 256, 0, stream>>>(edge_index, edge_type, offs, cursor,
                                                         sortedSrc, sortedT);
  agg_A1_kernel<<<(N_ENT + 3) / 4, 256, 0, stream>>>(offs, cnt, sortedSrc, sortedT,
                                                     ent_emb, rel_emb, A1);
  build_B1T<<<(256 * 416) / 256, 256, 0, stream>>>(W, W_loop, B1T);

  // all_ent = tanh([agg*norm | ent] @ [W ; W_loop]) -> bf16 [100000][224]
  // 1-D grid: 782 M-blocks x 2 N-blocks
  gemm_t<4, 2><<<782 * 2, 256, 0, stream>>>(A1, 416, B1T, 416, all_ent, AE_LD,
      416, 2, nullptr, 0, N_ENT, N_ENT, 200, AE_LD, nullptr, 1, 0.f,
      nullptr, nullptr, nullptr);

  // phase 2: folded-weight precomputes (f32; PQ/P2 die here)
  all_rel_kernel<<<474, 256, 0, stream>>>(rel_emb, W_rel, allrel);
  pq_kernel<<<(2 * 100 * 2048) / 256, 256, 0, stream>>>(allrel, w1, PQ);
  p2_kernel<<<(2 * 200 * 2048) / 256, 256, 0, stream>>>(trans_w, PQ, P2);
  w1eff_kernel<<<(2048 * 448) / 256, 256, 0, stream>>>(w1, P2, W1eff);
  b1eff_kernel<<<8, 256, 0, stream>>>(b1, trans_b, PQ, b1eff);
  qkw2_kernel<<<(128 * 224) / 256, 256, 0, stream>>>(trans_w, q_w, k_w, qw2T, kw2T);
  qkb2_kernel<<<1, 128, 0, stream>>>(q_b, k_b, trans_b, q_w, k_w, qb2, kb2);
  build_w2T<<<(512 * 2048) / 256, 256, 0, stream>>>(w2, w2T);

  // phase 3: atta = ((te0@qw2+qb2) . (te1@kw2+kb2)) / sqrt(200)  (gathered from all_ent)
  gemm_t<4, 2><<<1024, 256, 0, stream>>>(all_ent, AE_LD, qw2T, AE_LD, Qbuf, 128,
      AE_LD, 1, toTest, 2, 0, N_TEST, 128, 128, qb2, 0, 0.f,
      nullptr, nullptr, nullptr);
  gemm_t<4, 2><<<1024, 256, 0, stream>>>(all_ent, AE_LD, kw2T, AE_LD, nullptr, 0,
      AE_LD, 1, toTest, 3, 0, N_TEST, 128, 128, kb2, 3, 0.f,
      Qbuf, nullptr, atta);

  // phase 4: per-chunk  h1 = lrelu(dual[te0|te1] @ W1eff + atta*w1[400,:] + b1eff)
  //          logit += rowdot(lrelu(h1 @ w2T + b2), w3)  ;  then sigmoid
  // In-GEMM dual gather (r0-style; gather_te was net-negative, r5) +
  // XCD swizzle: per-XCD hot set {W1eff 1.8MB + M-panel rows} L2-resident.
  for (int c = 0; c < NC; ++c) {
    gemm_t<4, 2><<<(CH / 128) * 16, 256, 0, stream>>>(all_ent, AE_LD, W1eff, 448, h1, 2048,
        448, 16, toTest + (size_t)c * CH * 2, 4, 0, CH, 2048, 2048, b1eff, 5, 0.0001f,
        nullptr, w1 + (size_t)400 * 2048, atta + (size_t)c * CH);
    gemm_t<4, 2><<<(CH / 128) * 4, 256, 0, stream>>>(h1, 2048, w2T, 2048, nullptr, 0,
        2048, 4, nullptr, 0, CH, CH, 512, 512, b2, 4, 0.001f,
        nullptr, w3, logit + (size_t)c * CH);
  }
  sigmoid_kernel<<<N_TEST / 256, 256, 0, stream>>>(logit, b3, out);
}

// Round 8
// 1666.310 us; speedup vs baseline: 1.1496x; 1.0730x over previous
//
#include <hip/hip_runtime.h>

typedef unsigned short u16;
typedef unsigned long long u64;
typedef __attribute__((ext_vector_type(8))) short bf8;
typedef __attribute__((ext_vector_type(4))) float fx4;

#define N_ENT   100000
#define N_EDGE  500000
#define N_TEST  131072
#define EDIM    200
#define AE_LD   224     // all_ent leading dim (200 valid + 24 zero pad)
#define NB_SCAN 391     // ceil(100000/256)

// ---------- helpers ----------
__device__ __forceinline__ u16 f2bf(float f) {
  union { float f; unsigned u; } c; c.f = f;
  return (u16)((c.u + 0x7FFFu + ((c.u >> 16) & 1u)) >> 16);  // RNE
}
__device__ __forceinline__ float bf2f(u16 h) {
  union { unsigned u; float f; } c; c.u = ((unsigned)h) << 16;
  return c.f;
}
// async global->LDS, 16B per lane; LDS dest = wave-uniform base + lane*16
__device__ __forceinline__ void gload16(const u16* g, u16* l) {
  __builtin_amdgcn_global_load_lds(
      (const __attribute__((address_space(1))) void*)g,
      (__attribute__((address_space(3))) void*)l, 16, 0, 0);
}

// ---------- generic bf16 MFMA GEMM: out = act(A @ B^T + bias) ----------
// ENGINE: 128x128 tile, 4 waves, BK=32, ~2.5 blocks/CU, XCD-chunked block
// swizzle (r7: FETCH 72->55MB). NEW this round: T4 counted-vmcnt
// double-buffered K-loop. r4's dbuf failed because __syncthreads emits
// s_waitcnt vmcnt(0), draining the just-issued prefetch (serializing
// compute -> full load latency every tile). Raw s_barrier + asm
// "s_waitcnt vmcnt(4)" keeps the 4 prefetch loads in flight across the
// barrier while guaranteeing the current tile's 4 loads landed (m201's
// 8-phase proves gload_lds + raw barriers + counted vmcnt is sound; m98
// asm shows the compiler does NOT auto-drain before ds_read).
// sched_barrier(0) fences at phase boundaries pin the order (rule #18).
// Schedule/tile: STAGE(next) -> vmcnt(4) -> bar -> ds_read+MFMA(cur) -> bar.
// Post-compute barrier protects buf[next] (read at t-1) from t+1's STAGE.
// Staging swizzle (r3-verified, conflicts 7.86M->0.52M): source-side 16B-slot
// ^= (row>>1)&3 with linear LDS dest (m104); read slot = fq^((fr>>1)&3).
// idxMode: 0 none (clamp at mClamp), 2 rowIdx[2*gm], 3 rowIdx[2*gm+1],
//          4 dual-gather: cols <224 from rowIdx[2*gm], cols >=224 from rowIdx[2*gm+1]
// act: 0 none | 1 tanh | 3 dot-vs-qbuf -> dotOut (atta) | 4 lrelu,dot-auxF -> dotOut (logit)
//      5 store lrelu(acc + bias + dotOut[row]*auxF[col])
#define BK 32
#define EPS 72   // epilogue LDS row stride (u16)

template<int TM, int WN>
__global__ __launch_bounds__(64 * 2 * WN) void gemm_t(
    const u16* __restrict__ A, long lda,
    const u16* __restrict__ B, long ldb,
    u16* __restrict__ out, long ldOut,
    int K, int NBN,
    const int* __restrict__ rowIdx, int idxMode, int mClamp,
    int mValid, int nValid, int nStore,
    const float* __restrict__ bias, int act, float slope,
    const u16* __restrict__ qbuf, const float* __restrict__ auxF,
    float* __restrict__ dotOut)
{
  constexpr int BM = TM * 32;        // 2 wave-rows x TM*16
  constexpr int BN = WN * 64;
  constexpr int BUFS = (BM + BN) * BK;   // u16 per staging buffer (A|B)
  // double-buffered staging (2*BUFS u16 = 32KB for <4,2>); epilogue
  // (WAVES*32*EPS = 9216 u16) reuses the front of the buffer space.
  __shared__ __align__(16) u16 smem[2 * BUFS];
  const int tid  = threadIdx.x;
  const int wave = tid >> 6, lane = tid & 63;
  const int wr = (wave / WN) * (TM * 16), wc = (wave % WN) * 64;
  const int fr = lane & 15, fq = lane >> 4;

  // T1: bijective XCD-chunked swizzle (m204) + n-fastest decode.
  const int nwg = gridDim.x;
  const int orig = blockIdx.x;
  const int q = nwg >> 3, rr = nwg & 7;
  const int xcd = orig & 7, j = orig >> 3;
  const int wgid = (xcd < rr ? xcd * (q + 1) : rr * (q + 1) + (xcd - rr) * q) + j;
  const long bm = (long)(wgid / NBN) * BM;
  const long bn = (long)(wgid % NBN) * BN;

  // staging: wave stages rows [wave*32, +32) of A and B as 2 chunks of 16 rows;
  // chunk = 64 lanes x 16B; lane i -> row +i/4, swizzled 16B-slot (i&3)^((i>>3)&3).
  const int srow = wave * 32;
  const int kc = (((lane & 3) ^ ((lane >> 3) & 3)) * 8);   // swizzled source u16 col
  long a0[2], a1[2], boff[2];
  #pragma unroll
  for (int h = 0; h < 2; ++h) {
    long gmRow = bm + srow + h * 16 + (lane >> 2);
    long b0, b1;
    if (idxMode == 0) {
      long gm = (gmRow >= mClamp) ? (mClamp - 1) : gmRow;   // values unused (store-guarded)
      b0 = gm * lda; b1 = b0;
    } else if (idxMode == 2) {
      b0 = (long)rowIdx[2 * gmRow] * lda; b1 = b0;
    } else if (idxMode == 3) {
      b0 = (long)rowIdx[2 * gmRow + 1] * lda; b1 = b0;
    } else { // 4: dual
      b0 = (long)rowIdx[2 * gmRow] * lda;
      b1 = (long)rowIdx[2 * gmRow + 1] * lda - 224;
    }
    a0[h] = b0 + kc; a1[h] = b1 + kc;
    boff[h] = (bn + srow + h * 16 + (lane >> 2)) * ldb + kc;
  }

  // 4 gload_lds per STAGE -> vmcnt granularity is 4/tile.
  auto STAGE = [&](int buf, int k0) {
    u16* Ad = smem + buf * BUFS;
    u16* Bd = Ad + BM * BK;
    const bool lo = (k0 + kc) < 224;   // 16B slots never straddle 224 (224%32==0)
    #pragma unroll
    for (int h = 0; h < 2; ++h) {
      const long ao = (idxMode == 4) ? (lo ? a0[h] : a1[h]) : a0[h];
      gload16(A + ao + k0, &Ad[(srow + h * 16) * BK]);
      gload16(B + boff[h] + k0, &Bd[(srow + h * 16) * BK]);
    }
  };

  fx4 zero4 = {0.f, 0.f, 0.f, 0.f};
  fx4 acc[TM][4];
  #pragma unroll
  for (int i = 0; i < TM; ++i)
    #pragma unroll
    for (int j2 = 0; j2 < 4; ++j2) acc[i][j2] = zero4;

  const int NT = K / BK;
  STAGE(0, 0);
  for (int t = 0; t < NT; ++t) {
    const int cur = t & 1;
    if (t + 1 < NT) {
      STAGE(cur ^ 1, (t + 1) * BK);      // prefetch next tile (4 loads in flight)
      __builtin_amdgcn_sched_barrier(0);
      asm volatile("s_waitcnt vmcnt(4)" ::: "memory");   // cur's 4 loads done
    } else {
      __builtin_amdgcn_sched_barrier(0);
      asm volatile("s_waitcnt vmcnt(0)" ::: "memory");   // last tile: drain
    }
    __builtin_amdgcn_sched_barrier(0);
    __builtin_amdgcn_s_barrier();        // all waves' cur loads landed
    __builtin_amdgcn_sched_barrier(0);
    {
      const u16* Ac = smem + cur * BUFS;
      const u16* Bc = Ac + BM * BK;
      bf8 aF[TM], bF[4];
      const int rslot = (fq ^ ((fr >> 1) & 3)) * 8;   // read-side involution
      #pragma unroll
      for (int mt = 0; mt < TM; ++mt)
        aF[mt] = *(const bf8*)&Ac[(wr + mt * 16 + fr) * BK + rslot];
      #pragma unroll
      for (int nt = 0; nt < 4; ++nt)
        bF[nt] = *(const bf8*)&Bc[(wc + nt * 16 + fr) * BK + rslot];
      #pragma unroll
      for (int mt = 0; mt < TM; ++mt)
        #pragma unroll
        for (int nt = 0; nt < 4; ++nt)
          acc[mt][nt] = __builtin_amdgcn_mfma_f32_16x16x32_bf16(aF[mt], bF[nt], acc[mt][nt], 0, 0, 0);
    }
    __builtin_amdgcn_sched_barrier(0);
    __builtin_amdgcn_s_barrier();        // reads of cur consumed -> t+1 may overwrite
    __builtin_amdgcn_sched_barrier(0);
  }

  // C/D layout: col=lane&15, row=(lane>>4)*4+reg  [m89-verified]
  if (act == 3 || act == 4) {
    #pragma unroll
    for (int mt = 0; mt < TM; ++mt) {
      #pragma unroll
      for (int r = 0; r < 4; ++r) {
        const long gm = bm + wr + mt * 16 + fq * 4 + r;
        float p = 0.f;
        #pragma unroll
        for (int nt = 0; nt < 4; ++nt) {
          const long gn = bn + wc + nt * 16 + fr;
          float v = acc[mt][nt][r] + bias[gn];
          if (act == 3) p += v * bf2f(qbuf[gm * 128 + gn]);
          else { v = (v >= 0.f) ? v : v * slope; p += v * auxF[gn]; }
        }
        p += __shfl_xor(p, 1, 64); p += __shfl_xor(p, 2, 64);
        p += __shfl_xor(p, 4, 64); p += __shfl_xor(p, 8, 64);
        if (fr == 0 && gm < mValid)
          atomicAdd(&dotOut[gm], (act == 3) ? p * 0.07071067811865475f : p);  // 1/sqrt(200)
      }
    }
    return;
  }

  // store epilogue: wave tile (TM*16 x 64) in 32-row passes through a private
  // 32xEPS LDS region (wave-local ordering only; final K-loop barrier already
  // guaranteed all staging reads done before we overwrite).
  u16* ep = smem + wave * (32 * EPS);
  #pragma unroll
  for (int p = 0; p < TM / 2; ++p) {
    #pragma unroll
    for (int mt2 = 0; mt2 < 2; ++mt2) {
      const int mt = 2 * p + mt2;
      #pragma unroll
      for (int r = 0; r < 4; ++r) {
        const int lrl = mt2 * 16 + fq * 4 + r;       // row within the 32-row pass
        const long gm = bm + wr + mt * 16 + fq * 4 + r;
        const float attaV = (act == 5) ? dotOut[gm] : 0.f;
        #pragma unroll
        for (int nt = 0; nt < 4; ++nt) {
          const long gn = bn + wc + nt * 16 + fr;
          float v = 0.f;
          if (gn < nValid) {
            v = acc[mt][nt][r];
            if (bias) v += bias[gn];
            if (act == 1) v = tanhf(v);
            else if (act == 5) { v += attaV * auxF[gn]; v = (v >= 0.f) ? v : v * slope; }
          }
          ep[lrl * EPS + nt * 16 + fr] = f2bf(v);
        }
      }
    }
    // wave-local readback (compiler inserts lgkmcnt waits); 4 dwordx4 stores/lane
    #pragma unroll
    for (int it = 0; it < 4; ++it) {
      const int lr = it * 8 + (lane >> 3);
      const int lc = (lane & 7) * 8;
      const long gm = bm + wr + p * 32 + lr;
      const long gn = bn + wc + lc;
      if (gm < mValid && gn + 7 < nStore)
        *(bf8*)(out + gm * ldOut + gn) = *(const bf8*)&ep[lr * EPS + lc];
    }
  }
}

// ---------- sorted-CSR edge aggregation ----------
__global__ void hist_kernel(const int* __restrict__ ei, int* __restrict__ cnt) {
  int e = blockIdx.x * 256 + threadIdx.x;
  if (e < N_EDGE) atomicAdd(&cnt[ei[N_EDGE + e]], 1);
}
__global__ void scanA_kernel(const int* __restrict__ cnt, int* __restrict__ offs,
                             int* __restrict__ blockSums) {
  __shared__ int s[256];
  int gid = blockIdx.x * 256 + threadIdx.x;
  int v = (gid < N_ENT) ? cnt[gid] : 0;
  s[threadIdx.x] = v;
  __syncthreads();
  for (int off = 1; off < 256; off <<= 1) {
    int t = (threadIdx.x >= off) ? s[threadIdx.x - off] : 0;
    __syncthreads();
    s[threadIdx.x] += t;
    __syncthreads();
  }
  if (gid < N_ENT) offs[gid] = s[threadIdx.x] - v;
  if (threadIdx.x == 255) blockSums[blockIdx.x] = s[255];
}
__global__ void scanB_kernel(const int* __restrict__ blockSums, int* __restrict__ blockOffs) {
  __shared__ int s[512];
  int v = (threadIdx.x < NB_SCAN) ? blockSums[threadIdx.x] : 0;
  s[threadIdx.x] = v;
  __syncthreads();
  for (int off = 1; off < 512; off <<= 1) {
    int t = (threadIdx.x >= off) ? s[threadIdx.x - off] : 0;
    __syncthreads();
    s[threadIdx.x] += t;
    __syncthreads();
  }
  if (threadIdx.x < NB_SCAN) blockOffs[threadIdx.x] = s[threadIdx.x] - v;
}
__global__ void scanC_kernel(int* __restrict__ offs, const int* __restrict__ blockOffs) {
  int gid = blockIdx.x * 256 + threadIdx.x;
  if (gid < N_ENT) offs[gid] += blockOffs[blockIdx.x];
}
__global__ void place_kernel(const int* __restrict__ ei, const int* __restrict__ et,
                             const int* __restrict__ offs, int* __restrict__ cursor,
                             int* __restrict__ sortedSrc, int* __restrict__ sortedT) {
  int e = blockIdx.x * 256 + threadIdx.x;
  if (e >= N_EDGE) return;
  int dst = ei[N_EDGE + e];
  int pos = offs[dst] + atomicAdd(&cursor[dst], 1);
  sortedSrc[pos] = ei[e];
  sortedT[pos]   = et[e];
}
// wave-per-entity, float4: A1 row = [segsum(ent[src]-rel[t])*rsqrt(max(deg,1)) | ent_emb[r] | 0]
__global__ void agg_A1_kernel(const int* __restrict__ offs, const int* __restrict__ cnt,
                              const int* __restrict__ sortedSrc, const int* __restrict__ sortedT,
                              const float* __restrict__ ent_emb, const float* __restrict__ rel_emb,
                              u16* __restrict__ A1) {
  const int r = blockIdx.x * 4 + (threadIdx.x >> 6);
  if (r >= N_ENT) return;
  const int lane = threadIdx.x & 63;
  const int beg = offs[r], n = cnt[r];
  u16* row = A1 + (size_t)r * 416;
  if (lane < 50) {
    float4 a = {0.f, 0.f, 0.f, 0.f};
    for (int e = 0; e < n; ++e) {
      const int s = sortedSrc[beg + e], t = sortedT[beg + e];
      float4 x = ((const float4*)(ent_emb + (size_t)s * EDIM))[lane];
      float4 y = ((const float4*)(rel_emb + (size_t)t * EDIM))[lane];
      a.x += x.x - y.x; a.y += x.y - y.y; a.z += x.z - y.z; a.w += x.w - y.w;
    }
    const float nm = rsqrtf(fmaxf((float)n, 1.f));
    u64 p = (u64)f2bf(a.x * nm) | ((u64)f2bf(a.y * nm) << 16)
          | ((u64)f2bf(a.z * nm) << 32) | ((u64)f2bf(a.w * nm) << 48);
    *(u64*)(row + 4 * lane) = p;
    float4 e = ((const float4*)(ent_emb + (size_t)r * EDIM))[lane];
    u64 q = (u64)f2bf(e.x) | ((u64)f2bf(e.y) << 16)
          | ((u64)f2bf(e.z) << 32) | ((u64)f2bf(e.w) << 48);
    *(u64*)(row + 200 + 4 * lane) = q;
  }
  if (lane < 16) row[400 + lane] = 0;
}

// ---------- builders / precomputes ----------
__global__ void build_B1T(const float* __restrict__ W, const float* __restrict__ W_loop,
                          u16* __restrict__ B1T)
{
  int idx = blockIdx.x * 256 + threadIdx.x;
  if (idx >= 256 * 416) return;
  int n = idx / 416, k = idx % 416;
  float v = 0.f;
  if (n < 200) {
    if (k < 200) v = W[k * 200 + n];
    else if (k < 400) v = W_loop[(k - 200) * 200 + n];
  }
  B1T[idx] = f2bf(v);
}
__global__ void all_rel_kernel(const float* __restrict__ rel_emb, const float* __restrict__ W_rel,
                               float* __restrict__ all_rel)
{
  int r = blockIdx.x, c = threadIdx.x;
  if (c >= 200) return;
  const float* re = rel_emb + r * 200;
  float a = 0.f;
  for (int k = 0; k < 200; ++k) a += re[k] * W_rel[k * 200 + c];
  all_rel[r * 200 + c] = a;
}
// PQ[sel][m][n] = sum_r all_rel[r][sel*100+m] * w1[401+r][n]
__global__ void pq_kernel(const float* __restrict__ all_rel, const float* __restrict__ w1,
                          float* __restrict__ PQ) {
  int idx = blockIdx.x * 256 + threadIdx.x;
  if (idx >= 2 * 100 * 2048) return;
  int n = idx & 2047, m = (idx >> 11) % 100, sel = idx / 204800;
  float a = 0.f;
  for (int r = 0; r < 474; ++r)
    a += all_rel[r * 200 + sel * 100 + m] * w1[(size_t)(401 + r) * 2048 + n];
  PQ[idx] = a;
}
// P2[sel][k][n] = sum_m trans_w[k][m] * PQ[sel][m][n]
__global__ void p2_kernel(const float* __restrict__ trans_w, const float* __restrict__ PQ,
                          float* __restrict__ P2) {
  int idx = blockIdx.x * 256 + threadIdx.x;
  if (idx >= 2 * 200 * 2048) return;
  int n = idx & 2047, k = (idx >> 11) % 200, sel = idx / 409600;
  const float* pq = PQ + sel * 204800;
  float a = 0.f;
  for (int m = 0; m < 100; ++m) a += trans_w[k * 100 + m] * pq[m * 2048 + n];
  P2[idx] = a;
}
// W1eff [2048][448] B-layout: k<200: w1[k][n]+P2h ; 224<=k<424: w1[200+kk][n]-P2t ; else 0
__global__ void w1eff_kernel(const float* __restrict__ w1, const float* __restrict__ P2,
                             u16* __restrict__ W1eff) {
  int idx = blockIdx.x * 256 + threadIdx.x;
  if (idx >= 2048 * 448) return;
  int n = idx / 448, k = idx % 448;
  float v = 0.f;
  if (k < 200) v = w1[(size_t)k * 2048 + n] + P2[(size_t)k * 2048 + n];
  else if (k >= 224 && k < 424) {
    int kk = k - 224;
    v = w1[(size_t)(200 + kk) * 2048 + n] - P2[409600 + (size_t)kk * 2048 + n];
  }
  W1eff[idx] = f2bf(v);
}
__global__ void b1eff_kernel(const float* __restrict__ b1, const float* __restrict__ trans_b,
                             const float* __restrict__ PQ, float* __restrict__ b1eff) {
  int n = blockIdx.x * 256 + threadIdx.x;
  if (n >= 2048) return;
  float a = b1[n];
  for (int m = 0; m < 100; ++m)
    a += trans_b[m] * (PQ[m * 2048 + n] - PQ[204800 + m * 2048 + n]);
  b1eff[n] = a;
}
// qw2T/kw2T [128][224] B-layout: row j, col k<200: sum_m trans_w[k][m]*{q,k}_w[m][j]
__global__ void qkw2_kernel(const float* __restrict__ trans_w, const float* __restrict__ q_w,
                            const float* __restrict__ k_w, u16* __restrict__ qw2T,
                            u16* __restrict__ kw2T) {
  int idx = blockIdx.x * 256 + threadIdx.x;
  if (idx >= 128 * 224) return;
  int j = idx / 224, k = idx % 224;
  float a = 0.f, b = 0.f;
  if (k < 200)
    for (int m = 0; m < 100; ++m) {
      float t = trans_w[k * 100 + m];
      a += t * q_w[m * 128 + j];
      b += t * k_w[m * 128 + j];
    }
  qw2T[idx] = f2bf(a);
  kw2T[idx] = f2bf(b);
}
__global__ void qkb2_kernel(const float* __restrict__ q_b, const float* __restrict__ k_b,
                            const float* __restrict__ trans_b, const float* __restrict__ q_w,
                            const float* __restrict__ k_w, float* __restrict__ qb2,
                            float* __restrict__ kb2) {
  int j = threadIdx.x;
  if (j >= 128) return;
  float a = q_b[j], b = k_b[j];
  for (int m = 0; m < 100; ++m) {
    a += trans_b[m] * q_w[m * 128 + j];
    b += trans_b[m] * k_w[m * 128 + j];
  }
  qb2[j] = a; kb2[j] = b;
}
__global__ void build_w2T(const float* __restrict__ w2, u16* __restrict__ w2T)
{
  long idx = (long)blockIdx.x * 256 + threadIdx.x;
  if (idx >= (long)512 * 2048) return;
  int n = (int)(idx / 2048), k = (int)(idx % 2048);
  w2T[idx] = f2bf(w2[(size_t)k * 512 + n]);
}
__global__ void sigmoid_kernel(const float* __restrict__ logit, const float* __restrict__ b3,
                               float* __restrict__ out) {
  int i = blockIdx.x * 256 + threadIdx.x;
  if (i >= N_TEST) return;
  out[i] = 1.f / (1.f + __expf(-(logit[i] + b3[0])));
}

// ---------- host ----------
extern "C" void kernel_launch(void* const* d_in, const int* in_sizes, int n_in,
                              void* d_out, int out_size, void* d_ws, size_t ws_size,
                              hipStream_t stream)
{
  (void)in_sizes; (void)n_in; (void)out_size;
  const int*   edge_index = (const int*)d_in[0];
  const int*   edge_type  = (const int*)d_in[1];
  const int*   toTest     = (const int*)d_in[2];
  const float* ent_emb    = (const float*)d_in[3];
  const float* rel_emb    = (const float*)d_in[4];
  const float* W          = (const float*)d_in[5];
  const float* W_loop     = (const float*)d_in[6];
  const float* W_rel      = (const float*)d_in[7];
  const float* trans_w    = (const float*)d_in[8];
  const float* trans_b    = (const float*)d_in[9];
  const float* q_w        = (const float*)d_in[10];
  const float* q_b        = (const float*)d_in[11];
  const float* k_w        = (const float*)d_in[12];
  const float* k_b        = (const float*)d_in[13];
  const float* w1         = (const float*)d_in[14];
  const float* b1         = (const float*)d_in[15];
  const float* w2         = (const float*)d_in[16];
  const float* b2         = (const float*)d_in[17];
  const float* w3         = (const float*)d_in[18];
  const float* b3         = (const float*)d_in[19];
  float* out = (float*)d_out;

  // ---- workspace layout (lifetime overlays) ----
  unsigned char* ws = (unsigned char*)d_ws;
  float* atta    = (float*)(ws + 0);            //   524,288
  float* logit   = (float*)(ws + 524288);       //   524,288
  float* allrel  = (float*)(ws + 1048576);      //   379,392 (474*200*4 pad)
  u16*   B1T     = (u16*)  (ws + 1427968);      //   212,992
  u16*   W1eff   = (u16*)  (ws + 1640960);      // 1,835,008 (2048*448*2)
  u16*   qw2T    = (u16*)  (ws + 3475968);      //    57,344
  u16*   kw2T    = (u16*)  (ws + 3533312);      //    57,344
  float* b1eff   = (float*)(ws + 3590656);      //     8,192
  float* qb2     = (float*)(ws + 3598848);      //     1,024 (pad)
  float* kb2     = (float*)(ws + 3599872);      //     1,024 (pad)
  u16*   w2T     = (u16*)  (ws + 3600896);      // 2,097,152
  const size_t X_base = 5698048;
  u16*   all_ent = (u16*)  (ws + X_base);                  // 44,800,000
  u16*   Qbuf    = (u16*)  (ws + X_base + 44800000);       // 33,554,432
  const size_t Y_base = 84052480;
  u16*   A1      = (u16*)  (ws + Y_base);       // 83,200,000 (dead after all_ent GEMM)
  const size_t Z_base = 167252480;

  // Z scratch (dead after precomputes, before h1 is written)
  int*   cnt       = (int*)  (ws + Z_base);
  int*   offs      = (int*)  (ws + Z_base + 400000);
  int*   cursor    = (int*)  (ws + Z_base + 800000);
  int*   blockSums = (int*)  (ws + Z_base + 1200000);
  int*   blockOffs = (int*)  (ws + Z_base + 1202048);
  int*   sortedSrc = (int*)  (ws + Z_base + 1204096);
  int*   sortedT   = (int*)  (ws + Z_base + 3204096);
  float* PQ        = (float*)(ws + Z_base + 5204096);   // 1,638,400
  float* P2        = (float*)(ws + Z_base + 6842496);   // 3,276,800 -> ends Z+10,119,296

  int CH;
  if      (Z_base + (size_t)131072 * 4096 <= ws_size) CH = 131072;
  else if (Z_base + (size_t)65536  * 4096 <= ws_size) CH = 65536;
  else if (Z_base + (size_t)32768  * 4096 <= ws_size) CH = 32768;
  else if (Z_base + (size_t)16384  * 4096 <= ws_size) CH = 16384;
  else if (Z_base + (size_t)8192   * 4096 <= ws_size) CH = 8192;
  else return;
  u16* h1 = (u16*)(ws + Z_base);                 // CH*2048*2 (overlays dead scratch)
  const int NC = N_TEST / CH;

  hipMemsetAsync(cnt, 0, 400000, stream);
  hipMemsetAsync(cursor, 0, 400000, stream);
  hipMemsetAsync(atta, 0, 524288, stream);
  hipMemsetAsync(logit, 0, 524288, stream);

  // phase 1: CSR aggregation -> A1
  hist_kernel<<<(N_EDGE + 255) / 256, 256, 0, stream>>>(edge_index, cnt);
  scanA_kernel<<<NB_SCAN, 256, 0, stream>>>(cnt, offs, blockSums);
  scanB_kernel<<<1, 512, 0, stream>>>(blockSums, blockOffs);
  scanC_kernel<<<NB_SCAN, 256, 0, stream>>>(offs, blockOffs);
  place_kernel<<<(N_EDGE + 255) / 256, 256, 0, stream>>>(edge_index, edge_type, offs, cursor,
                                                         sortedSrc, sortedT);
  agg_A1_kernel<<<(N_ENT + 3) / 4, 256, 0, stream>>>(offs, cnt, sortedSrc, sortedT,
                                                     ent_emb, rel_emb, A1);
  build_B1T<<<(256 * 416) / 256, 256, 0, stream>>>(W, W_loop, B1T);

  // all_ent = tanh([agg*norm | ent] @ [W ; W_loop]) -> bf16 [100000][224]
  // 1-D grid: 782 M-blocks x 2 N-blocks
  gemm_t<4, 2><<<782 * 2, 256, 0, stream>>>(A1, 416, B1T, 416, all_ent, AE_LD,
      416, 2, nullptr, 0, N_ENT, N_ENT, 200, AE_LD, nullptr, 1, 0.f,
      nullptr, nullptr, nullptr);

  // phase 2: folded-weight precomputes (f32; PQ/P2 die here)
  all_rel_kernel<<<474, 256, 0, stream>>>(rel_emb, W_rel, allrel);
  pq_kernel<<<(2 * 100 * 2048) / 256, 256, 0, stream>>>(allrel, w1, PQ);
  p2_kernel<<<(2 * 200 * 2048) / 256, 256, 0, stream>>>(trans_w, PQ, P2);
  w1eff_kernel<<<(2048 * 448) / 256, 256, 0, stream>>>(w1, P2, W1eff);
  b1eff_kernel<<<8, 256, 0, stream>>>(b1, trans_b, PQ, b1eff);
  qkw2_kernel<<<(128 * 224) / 256, 256, 0, stream>>>(trans_w, q_w, k_w, qw2T, kw2T);
  qkb2_kernel<<<1, 128, 0, stream>>>(q_b, k_b, trans_b, q_w, k_w, qb2, kb2);
  build_w2T<<<(512 * 2048) / 256, 256, 0, stream>>>(w2, w2T);

  // phase 3: atta = ((te0@qw2+qb2) . (te1@kw2+kb2)) / sqrt(200)  (gathered from all_ent)
  gemm_t<4, 2><<<1024, 256, 0, stream>>>(all_ent, AE_LD, qw2T, AE_LD, Qbuf, 128,
      AE_LD, 1, toTest, 2, 0, N_TEST, 128, 128, qb2, 0, 0.f,
      nullptr, nullptr, nullptr);
  gemm_t<4, 2><<<1024, 256, 0, stream>>>(all_ent, AE_LD, kw2T, AE_LD, nullptr, 0,
      AE_LD, 1, toTest, 3, 0, N_TEST, 128, 128, kb2, 3, 0.f,
      Qbuf, nullptr, atta);

  // phase 4: per-chunk  h1 = lrelu(dual[te0|te1] @ W1eff + atta*w1[400,:] + b1eff)
  //          logit += rowdot(lrelu(h1 @ w2T + b2), w3)  ;  then sigmoid
  for (int c = 0; c < NC; ++c) {
    gemm_t<4, 2><<<(CH / 128) * 16, 256, 0, stream>>>(all_ent, AE_LD, W1eff, 448, h1, 2048,
        448, 16, toTest + (size_t)c * CH * 2, 4, 0, CH, 2048, 2048, b1eff, 5, 0.0001f,
        nullptr, w1 + (size_t)400 * 2048, atta + (size_t)c * CH);
    gemm_t<4, 2><<<(CH / 128) * 4, 256, 0, stream>>>(h1, 2048, w2T, 2048, nullptr, 0,
        2048, 4, nullptr, 0, CH, CH, 512, 512, b2, 4, 0.001f,
        nullptr, w3, logit + (size_t)c * CH);
  }
  sigmoid_kernel<<<N_TEST / 256, 256, 0, stream>>>(logit, b3, out);
}